// Round 1
// 134.489 us; speedup vs baseline: 1.0432x; 1.0432x over previous
//
#include <hip/hip_runtime.h>
#include <stdint.h>

typedef __bf16 bf16x8 __attribute__((ext_vector_type(8)));
typedef float floatx4 __attribute__((ext_vector_type(4)));
typedef unsigned int u32x4 __attribute__((ext_vector_type(4)));
typedef unsigned short u16;
typedef unsigned short u16x8 __attribute__((ext_vector_type(8)));
typedef unsigned int u32;

#define CIN   64
#define COUT  128
#define H_    1855
#define KNB   6
#define KTOT  448      // (1+KNB)*CIN
#define NSTEPS 14      // KTOT / 32

// LDS geometry (bytes): piece (hl,s) = 256 B; hl row = 8 s-slots = 2048 B,
// padded +16 -> 2064 so B-frag reads spread all 32 banks. Buffer = 16 hl.
#define HLROW 2064
#define BUFSZ 33024

// ws layout (bytes)
#define WP_OFF     ((size_t)H_ * 4096 * 2)                 // xt3: bf16 [h][4096]
#define CINV_OFF   (WP_OFF + (size_t)COUT * KTOT * 2)
#define ZERO_OFF   (CINV_OFF + 7424)                       // 256-B aligned zero page
#define SRCOFF_OFF (ZERO_OFF + 1024)                       // u32 [H][8] gather row offsets
#define INVOFF 0xFFFFFFFFu

#define PIN4(v) asm volatile("" : "+v"(v))

typedef __attribute__((address_space(1))) unsigned int as1_u32;
typedef __attribute__((address_space(3))) unsigned int as3_u32;
static __device__ __forceinline__ void ld16_to_lds(const void* g, void* l) {
    __builtin_amdgcn_global_load_lds((const as1_u32*)g, (as3_u32*)l, 16, 0, 0);
}

static __device__ inline u16 f32_to_bf16(float f) {
    u32 u = __float_as_uint(f);
    u32 r = (u + 0x7FFFu + ((u >> 16) & 1u)) >> 16;
    return (u16)r;
}

// ---- K1: transpose x f32 [bc][h] -> xt3 bf16 [h][bc] ---------------------
__global__ __launch_bounds__(256) void k_transpose(const float* __restrict__ x,
                                                   u16* __restrict__ xt3) {
    __shared__ u16 tile[64][65];
    int h0  = blockIdx.x * 64;
    int bc0 = blockIdx.y * 64;
    int tid  = threadIdx.x;
    int lane = tid & 63;
    int rowq = tid >> 6;
    int h = h0 + lane;
    bool hv = h < H_;
#pragma unroll
    for (int i = 0; i < 16; ++i) {
        int row = i * 4 + rowq;
        u16 v = 0;
        if (hv) v = f32_to_bf16(x[(size_t)(bc0 + row) * H_ + h]);
        tile[row][lane] = v;
    }
    __syncthreads();
    // phase 2 vectorized: each thread packs 8 bc (u16x8) for one h -> one 16-B store.
    int bg = tid & 7;        // bc group of 8
    int hb = tid >> 3;       // 0..31
#pragma unroll
    for (int ii = 0; ii < 2; ++ii) {
        int hl = ii * 32 + hb;
        int hh = h0 + hl;
        u16x8 v;
#pragma unroll
        for (int j = 0; j < 8; ++j) v[j] = tile[bg * 8 + j][hl];
        if (hh < H_)
            *(u16x8*)(xt3 + (size_t)hh * 4096 + bc0 + bg * 8) = v;
    }
}

// ---- K2: pack weights + inverse counts + zero page + gather-offset table --
__global__ __launch_bounds__(256) void k_pack(const float* __restrict__ wc,
                                              const float* __restrict__ wn,
                                              const int* __restrict__ nbr,
                                              u16* __restrict__ wp,
                                              float* __restrict__ cInvG,
                                              u32* __restrict__ zeroPg,
                                              u32* __restrict__ srcOff) {
    int tg = blockIdx.x * 256 + threadIdx.x;
    if (tg < 64) zeroPg[tg] = 0u;            // 256-B zero page
    if (tg < H_) {
        int cnt = 1;
#pragma unroll
        for (int j = 0; j < KNB; ++j) cnt += (nbr[tg * KNB + j] >= 0) ? 1 : 0;
        cInvG[tg] = 1.0f / (float)cnt;
    }
    // srcOff[h][s]: byte offset of source row in xt3, or INVOFF (-> zero page).
    if (tg < H_ * 8) {
        int h = tg >> 3, s = tg & 7;
        u32 e;
        if (s == 0) e = (u32)h * 8192u;
        else if (s <= 6) {
            int n = nbr[h * KNB + (s - 1)];
            e = (n >= 0) ? (u32)n * 8192u : INVOFF;
        } else e = INVOFF;
        srcOff[tg] = e;
    }
    if (tg >= COUT * KTOT) return;
    int o = tg / KTOT;
    int rem = tg - o * KTOT;
    int s = rem >> 6, c = rem & 63;
    float v = (s == 0) ? wc[o * CIN + c]
                       : wn[(o * CIN + c) * KNB + (s - 1)];
    wp[tg] = f32_to_bf16(v);
}

// ---- K3: main gather-GEMM ------------------------------------------------
// grid = 928 = 29 h-supertiles x 32 b-pairs (XCD = blk&7). Block: 4 tiles of
// N=32 (2b x 16h), M=128 o, K=448. Schedule: raw s_barrier + counted vmcnt
// (T4): stores never drained at a barrier right after issue; prefetch loads
// retired with vmcnt(32) while 32 stores stay in flight. Pair epilogue emits
// 32-h (128-B) store segments to kill write amplification.
__global__ __launch_bounds__(256, 2) void k_main(const u16* __restrict__ xt3,
                                                 const u16* __restrict__ wp,
                                                 const float* __restrict__ bias,
                                                 const float* __restrict__ cInvG,
                                                 const u32* __restrict__ srcOff,
                                                 float* __restrict__ out) {
    __shared__ __align__(16) char LDS[2 * BUFSZ];

    int tid  = threadIdx.x;
    int gbl  = blockIdx.x;
    int bp   = gbl & 31;          // b-pair; XCD = gbl&7
    int hs   = gbl >> 5;          // 0..28
    int b0   = bp * 2;
    int h0   = hs * 64;

    int lane = tid & 63;
    int wave = tid >> 6;
    int col  = lane & 15;
    int quad = lane >> 4;
    int m0w  = wave * 32;
    int lane16 = lane & 15;
    int ssub = lane >> 4;         // s sub-index for staging (== quad)
    int bl   = lane16 >> 3;
    int chunk = lane16 & 7;

    const char* xb = (const char*)xt3;   // == d_ws base; all offsets relative

    // A fragments (weights): A[m=lane&15][k=quad*8+j], pinned.
    u32x4 afrag[2][NSTEPS];
#pragma unroll
    for (int mt = 0; mt < 2; ++mt) {
        int o = m0w + mt * 16 + col;
#pragma unroll
        for (int kk = 0; kk < NSTEPS; ++kk)
            afrag[mt][kk] = *(const u32x4*)(wp + o * KTOT + kk * 32 + quad * 8);
    }
#pragma unroll
    for (int mt = 0; mt < 2; ++mt)
#pragma unroll
        for (int kk = 0; kk < NSTEPS; ++kk)
            PIN4(afrag[mt][kk]);

    float biasv[2][4];
#pragma unroll
    for (int mt = 0; mt < 2; ++mt)
#pragma unroll
        for (int r = 0; r < 4; ++r)
            biasv[mt][r] = bias[m0w + mt * 16 + quad * 4 + r];

    float icv[4];                 // 1/count per tile, hoisted out of the loop
#pragma unroll
    for (int t = 0; t < 4; ++t) {
        int hic = h0 + t * 16 + col;
        icv[t] = cInvG[hic < H_ ? hic : 0];
    }

    // Precompute all 32 per-lane staging byte-offsets (kills the dependent
    // nbr-load chain in the hot loop; staging = pure global_load_lds issue).
    u32 colOff = (u32)((b0 + bl) * 128 + chunk * 16);
    u32 zOff   = (u32)ZERO_OFF + (u32)(lane16 * 16);
    u32 offs[4][8];
#pragma unroll
    for (int t = 0; t < 4; ++t)
#pragma unroll
        for (int i = 0; i < 8; ++i) {
            int hh = h0 + t * 16 + wave * 4 + (i & 3);
            int s  = (i >> 2) * 4 + ssub;
            u32 e = (hh < H_) ? srcOff[hh * 8 + s] : INVOFF;
            offs[t][i] = (e == INVOFF) ? zOff : (e + colOff);
        }

    int rb0 = col * HLROW + quad * 16;
    int rb1 = rb0 + 128;
    char* buf0 = LDS;
    char* buf1 = LDS + BUFSZ;
    float* E = (float*)(LDS + BUFSZ);    // pair-epilogue C-stage (128x64 f32 = 32 KB)

#define STAGE(t, bufp) do {                                                   \
    char* _d = (bufp) + (wave * 4) * HLROW;                                   \
    _Pragma("unroll")                                                         \
    for (int _i = 0; _i < 8; ++_i)                                            \
        ld16_to_lds(xb + offs[t][_i], _d + (_i & 3) * HLROW + (_i >> 2) * 1024); \
} while (0)

#define COMPUTE(accv, bufp) do {                                              \
    _Pragma("unroll") for (int _m = 0; _m < 2; ++_m)                          \
    _Pragma("unroll") for (int _n = 0; _n < 2; ++_n)                          \
        accv[_m][_n] = (floatx4){0.0f, 0.0f, 0.0f, 0.0f};                     \
    __builtin_amdgcn_s_setprio(1);                                            \
    _Pragma("unroll")                                                         \
    for (int kk = 0; kk < NSTEPS; ++kk) {                                     \
        int koff = (kk >> 1) * 256 + (kk & 1) * 64;                           \
        bf16x8 bfa = *(const bf16x8*)((bufp) + rb0 + koff);                   \
        bf16x8 bfb = *(const bf16x8*)((bufp) + rb1 + koff);                   \
        bf16x8 a0 = __builtin_bit_cast(bf16x8, afrag[0][kk]);                 \
        bf16x8 a1 = __builtin_bit_cast(bf16x8, afrag[1][kk]);                 \
        accv[0][0] = __builtin_amdgcn_mfma_f32_16x16x32_bf16(a0, bfa, accv[0][0], 0, 0, 0); \
        accv[1][0] = __builtin_amdgcn_mfma_f32_16x16x32_bf16(a1, bfa, accv[1][0], 0, 0, 0); \
        accv[0][1] = __builtin_amdgcn_mfma_f32_16x16x32_bf16(a0, bfb, accv[0][1], 0, 0, 0); \
        accv[1][1] = __builtin_amdgcn_mfma_f32_16x16x32_bf16(a1, bfb, accv[1][1], 0, 0, 0); \
    }                                                                         \
    __builtin_amdgcn_s_setprio(0);                                            \
} while (0)

// E write: row = o (0..127), idx = (b*32 + t*16 + col) ^ (quad<<3).
// XOR swizzle makes scatter-write and row-read both 2-way on banks (free).
#define EPIW(pp, t, accv) do {                                                \
    float _ic = icv[(pp) * 2 + (t)];                                          \
    _Pragma("unroll") for (int _m = 0; _m < 2; ++_m)                          \
    _Pragma("unroll") for (int _n = 0; _n < 2; ++_n)                          \
    _Pragma("unroll") for (int _r = 0; _r < 4; ++_r) {                        \
        int _row = m0w + _m * 16 + quad * 4 + _r;                             \
        int _idx = ((_n) * 32 + (t) * 16 + col) ^ (quad << 3);                \
        E[_row * 64 + _idx] = accv[_m][_n][_r] * _ic + biasv[_m][_r];         \
    }                                                                         \
} while (0)

// readback + store: lane = (g=b, h5 = 32 consecutive h) -> 128-B segments.
#define EPIS(pp) do {                                                         \
    int _h5 = lane & 31, _g = lane >> 5;                                      \
    int _hh = h0 + (pp) * 32 + _h5;                                           \
    bool _hv = _hh < H_;                                                      \
    size_t _ob = (size_t)(b0 + _g) * ((size_t)COUT * H_)                      \
               + (size_t)m0w * H_ + _hh;                                      \
    _Pragma("unroll")                                                         \
    for (int _j = 0; _j < 32; ++_j) {                                         \
        float _v = E[(m0w + _j) * 64 + ((_g * 32 + _h5) ^ (((_j >> 2) & 3) << 3))]; \
        if (_hv) out[_ob + (size_t)_j * H_] = _v;                             \
    }                                                                         \
} while (0)

// barriers: A = staging visibility (counted vmcnt), B = LDS handoff only.
#define ABAR0()  do { asm volatile("s_waitcnt vmcnt(0) lgkmcnt(0)" ::: "memory");  __builtin_amdgcn_s_barrier(); } while (0)
#define ABAR32() do { asm volatile("s_waitcnt vmcnt(32) lgkmcnt(0)" ::: "memory"); __builtin_amdgcn_s_barrier(); } while (0)
#define BBAR()   do { asm volatile("s_waitcnt lgkmcnt(0)" ::: "memory");           __builtin_amdgcn_s_barrier(); } while (0)

    floatx4 accA[2][2], accB[2][2];

    STAGE(0, buf0);               // FIFO: 8L
    ABAR0();                      // A0: t0 visible (also drains prologue loads)
    STAGE(1, buf1);               // 8L
    COMPUTE(accA, buf0);          // t0
    ABAR0();                      // A1: t1 visible (loads aged one compute phase)
    STAGE(2, buf0);               // 8L (all waves done with t0 via A1)
    COMPUTE(accB, buf1);          // t1
    BBAR();                       // B1: buf1 reads done block-wide; NO vm drain
    EPIW(0, 0, accA);
    EPIW(0, 1, accB);
    EPIS(0);                      // 32 stores (pair0); FIFO: [8L t2][32S]
    ABAR32();                     // A2: retires only the 8 t2 loads; stores fly on
    STAGE(3, buf1);               // overwrites E (consumed: lgkmcnt(0)+barrier above)
    COMPUTE(accA, buf0);          // t2
    ABAR0();                      // A3: t3 visible (stores now 1 phase old, cheap)
    COMPUTE(accB, buf1);          // t3
    BBAR();                       // B3
    EPIW(1, 0, accA);
    EPIW(1, 1, accB);
    EPIS(1);                      // final stores drain at endpgm

#undef STAGE
#undef COMPUTE
#undef EPIW
#undef EPIS
#undef ABAR0
#undef ABAR32
#undef BBAR
}

extern "C" void kernel_launch(void* const* d_in, const int* in_sizes, int n_in,
                              void* d_out, int out_size, void* d_ws, size_t ws_size,
                              hipStream_t stream) {
    const float* x    = (const float*)d_in[0];   // f32 [64,64,1855]
    const int*   nbr  = (const int*)d_in[1];     // int32 [1855,6]
    const float* wc   = (const float*)d_in[2];   // f32 [128,64]
    const float* wn   = (const float*)d_in[3];   // f32 [128,64,6]
    const float* bias = (const float*)d_in[4];   // f32 [128]

    u16*   xt3    = (u16*)d_ws;
    u16*   wp     = (u16*)((char*)d_ws + WP_OFF);
    float* cInvG  = (float*)((char*)d_ws + CINV_OFF);
    u32*   zeroPg = (u32*)((char*)d_ws + ZERO_OFF);
    u32*   srcOff = (u32*)((char*)d_ws + SRCOFF_OFF);

    k_pack<<<dim3((COUT * KTOT + 255) / 256), dim3(256), 0, stream>>>(
        wc, wn, nbr, wp, cInvG, zeroPg, srcOff);
    k_transpose<<<dim3(29, 64), dim3(256), 0, stream>>>(x, xt3);
    k_main<<<dim3(928), dim3(256), 0, stream>>>(
        xt3, wp, bias, cInvG, srcOff, (float*)d_out);
}